// Round 1
// baseline (289.315 us; speedup 1.0000x reference)
//
#include <hip/hip_runtime.h>
#include <stdint.h>

#define M_DIM 8192
#define N_DIM 4096
#define K_DIM 4096

typedef float f32x4 __attribute__((ext_vector_type(4)));
typedef uint32_t u32;

// ---------- helpers ----------

__device__ __forceinline__ void gload_lds16(const void* g, void* l) {
  // async global -> LDS, 16B per lane. LDS dest must be wave-uniform base + lane*16.
  __builtin_amdgcn_global_load_lds(
      (__attribute__((address_space(1))) void*)(g),
      (__attribute__((address_space(3))) void*)(l), 16, 0, 0);
}

__device__ __forceinline__ float clipdiv(float v, float s) {
  v = v / s;
  return fminf(fmaxf(v, -448.f), 448.f);
}

__device__ __forceinline__ u32 pack4_fp8(float a, float b, float c, float d) {
  // v_cvt_pk_fp8_f32: RNE, OCP e4m3fn on gfx950. byte0=a byte1=b byte2=c byte3=d
  int w = __builtin_amdgcn_cvt_pk_fp8_f32(a, b, 0, false);
  w = __builtin_amdgcn_cvt_pk_fp8_f32(c, d, w, true);
  return (u32)w;
}

// ---------- quantize A (row-major M x K, f32 -> e4m3fn) ----------

__global__ __launch_bounds__(256) void quant_a(const float* __restrict__ x,
                                               u32* __restrict__ q,
                                               const float* __restrict__ scale,
                                               int nv4) {
  int base = blockIdx.x * 1024 + threadIdx.x;
  float s = scale[0];
#pragma unroll
  for (int r = 0; r < 4; ++r) {
    int idx = base + r * 256;
    if (idx < nv4) {
      float4 v = ((const float4*)x)[idx];
      q[idx] = pack4_fp8(clipdiv(v.x, s), clipdiv(v.y, s),
                         clipdiv(v.z, s), clipdiv(v.w, s));
    }
  }
}

// ---------- quantize + transpose B (K x N f32 -> N x K fp8) ----------

__global__ __launch_bounds__(256) void quant_b_t(const float* __restrict__ B,
                                                 uint8_t* __restrict__ qT,
                                                 const float* __restrict__ scale) {
  __shared__ __align__(16) uint8_t lt[64 * 80];  // 64 n-rows x 64 k-bytes, +16B pad
  int tid = threadIdx.x;
  int kt = blockIdx.x * 64;  // k tile origin
  int nt = blockIdx.y * 64;  // n tile origin
  float s = scale[0];

  int kl = tid >> 4;          // 0..15
  int n4 = (tid & 15) * 4;    // 0..60
#pragma unroll
  for (int rep = 0; rep < 4; ++rep) {
    int k = kl + rep * 16;
    float4 v = *(const float4*)&B[(long)(kt + k) * N_DIM + nt + n4];
    u32 w = pack4_fp8(clipdiv(v.x, s), clipdiv(v.y, s),
                      clipdiv(v.z, s), clipdiv(v.w, s));
    lt[(n4 + 0) * 80 + k] = (uint8_t)(w & 0xff);
    lt[(n4 + 1) * 80 + k] = (uint8_t)((w >> 8) & 0xff);
    lt[(n4 + 2) * 80 + k] = (uint8_t)((w >> 16) & 0xff);
    lt[(n4 + 3) * 80 + k] = (uint8_t)(w >> 24);
  }
  __syncthreads();
  int n = tid >> 2, ch = tid & 3;
  uint4 o = *(const uint4*)&lt[n * 80 + ch * 16];
  *(uint4*)&qT[(long)(nt + n) * K_DIM + kt + ch * 16] = o;
}

// ---------- fp8 GEMM: C[M,N] = (Aq @ BqT^T) * sA*sB ----------
// 128x128 tile, BK=64, 4 waves (2x2), each wave 64x64 = 4x4 frags of 16x16x32.
// LDS granule swizzle: physical 16B-granule = logical ^ ((row>>1)&3)
// applied on BOTH the global staging source and the ds_read address.

__global__ __launch_bounds__(256) void gemm_fp8(const uint8_t* __restrict__ Aq,
                                                const uint8_t* __restrict__ BqT,
                                                float* __restrict__ C,
                                                const float* __restrict__ sA,
                                                const float* __restrict__ sB) {
  __shared__ __align__(16) uint8_t As[128 * 64];
  __shared__ __align__(16) uint8_t Bs[128 * 64];

  int tid = threadIdx.x;
  int lane = tid & 63;
  int w = tid >> 6;
  int wr = w >> 1, wc = w & 1;
  long bm = (long)blockIdx.y * 128;
  long bn = (long)blockIdx.x * 128;

  // --- staging addresses (2 granules of 16B per thread per matrix) ---
  int g0 = tid, g1 = tid + 256;
  int r0 = g0 >> 2, r1 = g1 >> 2;
  int cg0 = (g0 & 3) ^ ((r0 >> 1) & 3);  // pre-swizzled source granule
  int cg1 = (g1 & 3) ^ ((r1 >> 1) & 3);
  const uint8_t* gA0 = Aq + (bm + r0) * K_DIM + cg0 * 16;
  const uint8_t* gA1 = Aq + (bm + r1) * K_DIM + cg1 * 16;
  const uint8_t* gB0 = BqT + (bn + r0) * K_DIM + cg0 * 16;
  const uint8_t* gB1 = BqT + (bn + r1) * K_DIM + cg1 * 16;
  uint8_t* lA0 = As + g0 * 16;
  uint8_t* lA1 = As + g1 * 16;
  uint8_t* lB0 = Bs + g0 * 16;
  uint8_t* lB1 = Bs + g1 * 16;

  // --- fragment read offsets (loop-invariant, swizzled) ---
  int r16 = lane & 15;
  int hi = lane >> 4;        // 0..3
  int off8 = (hi & 1) * 8;   // byte within 16B granule
  int hi2 = hi >> 1;         // 0..1: which granule half of the 32-k step
  int offA[4][2], offB[4][2];
#pragma unroll
  for (int i = 0; i < 4; ++i) {
    int ra = wr * 64 + i * 16 + r16;
    int rb = wc * 64 + i * 16 + r16;
    int sa = (ra >> 1) & 3, sb = (rb >> 1) & 3;
#pragma unroll
    for (int kk = 0; kk < 2; ++kk) {
      offA[i][kk] = ra * 64 + ((((kk << 1) + hi2) ^ sa) << 4) + off8;
      offB[i][kk] = rb * 64 + ((((kk << 1) + hi2) ^ sb) << 4) + off8;
    }
  }

  f32x4 acc[4][4] = {};

  for (int t = 0; t < K_DIM / 64; ++t) {
    long ko = (long)t * 64;
    gload_lds16(gA0 + ko, lA0);
    gload_lds16(gA1 + ko, lA1);
    gload_lds16(gB0 + ko, lB0);
    gload_lds16(gB1 + ko, lB1);
    __syncthreads();  // drains vmcnt + lgkmcnt, then s_barrier

#pragma unroll
    for (int kk = 0; kk < 2; ++kk) {
      long long a0 = *(const long long*)(As + offA[0][kk]);
      long long a1 = *(const long long*)(As + offA[1][kk]);
      long long a2 = *(const long long*)(As + offA[2][kk]);
      long long a3 = *(const long long*)(As + offA[3][kk]);
      long long b0 = *(const long long*)(Bs + offB[0][kk]);
      long long b1 = *(const long long*)(Bs + offB[1][kk]);
      long long b2 = *(const long long*)(Bs + offB[2][kk]);
      long long b3 = *(const long long*)(Bs + offB[3][kk]);
      long long a[4] = {a0, a1, a2, a3};
      long long b[4] = {b0, b1, b2, b3};
#pragma unroll
      for (int i = 0; i < 4; ++i)
#pragma unroll
        for (int j = 0; j < 4; ++j)
          acc[i][j] = __builtin_amdgcn_mfma_f32_16x16x32_fp8_fp8(a[i], b[j],
                                                                 acc[i][j], 0, 0, 0);
    }
    __syncthreads();
  }

  float s = sA[0] * sB[0];
#pragma unroll
  for (int i = 0; i < 4; ++i)
#pragma unroll
    for (int j = 0; j < 4; ++j) {
      long row = bm + wr * 64 + i * 16 + hi * 4;  // C/D: row=(lane>>4)*4+q
      long col = bn + wc * 64 + j * 16 + r16;     //      col=lane&15
      float* cp = C + row * N_DIM + col;
#pragma unroll
      for (int q = 0; q < 4; ++q) cp[(long)q * N_DIM] = acc[i][j][q] * s;
    }
}

// ---------- launcher ----------

extern "C" void kernel_launch(void* const* d_in, const int* in_sizes, int n_in,
                              void* d_out, int out_size, void* d_ws, size_t ws_size,
                              hipStream_t stream) {
  const float* A = (const float*)d_in[0];        // (8192, 4096)
  const float* B = (const float*)d_in[1];        // (4096, 4096)
  const float* sA = (const float*)d_in[2];       // input_scale
  const float* sB = (const float*)d_in[4];       // kernel_scale
  float* out = (float*)d_out;

  uint8_t* Aq = (uint8_t*)d_ws;                          // M*K fp8
  uint8_t* BqT = Aq + (size_t)M_DIM * K_DIM;             // N*K fp8 (transposed)

  int nv4_a = M_DIM * K_DIM / 4;
  quant_a<<<nv4_a / 1024, 256, 0, stream>>>(A, (u32*)Aq, sA, nv4_a);
  quant_b_t<<<dim3(K_DIM / 64, N_DIM / 64), 256, 0, stream>>>(B, BqT, sB);
  gemm_fp8<<<dim3(N_DIM / 128, M_DIM / 128), 256, 0, stream>>>(Aq, BqT, out, sA, sB);
}

// Round 2
// 211.811 us; speedup vs baseline: 1.3659x; 1.3659x over previous
//
#include <hip/hip_runtime.h>
#include <stdint.h>

#define M_DIM 8192
#define N_DIM 4096
#define K_DIM 4096

typedef float f32x4 __attribute__((ext_vector_type(4)));
typedef int v4i __attribute__((ext_vector_type(4)));
typedef int v8i __attribute__((ext_vector_type(8)));
typedef uint32_t u32;

// ---------- helpers ----------

__device__ __forceinline__ void gload_lds16(const void* g, void* l) {
  // async global -> LDS, 16B per lane. LDS dest must be wave-uniform base + lane*16.
  __builtin_amdgcn_global_load_lds(
      (__attribute__((address_space(1))) void*)(g),
      (__attribute__((address_space(3))) void*)(l), 16, 0, 0);
}

__device__ __forceinline__ float clipdiv(float v, float s) {
  v = v / s;
  return fminf(fmaxf(v, -448.f), 448.f);
}

__device__ __forceinline__ u32 pack4_fp8(float a, float b, float c, float d) {
  // v_cvt_pk_fp8_f32: RNE, OCP e4m3fn on gfx950. byte0=a byte1=b byte2=c byte3=d
  int w = __builtin_amdgcn_cvt_pk_fp8_f32(a, b, 0, false);
  w = __builtin_amdgcn_cvt_pk_fp8_f32(c, d, w, true);
  return (u32)w;
}

// ---------- quantize A (row-major M x K, f32 -> e4m3fn) ----------

__global__ __launch_bounds__(256) void quant_a(const float* __restrict__ x,
                                               u32* __restrict__ q,
                                               const float* __restrict__ scale,
                                               int nv4) {
  int base = blockIdx.x * 1024 + threadIdx.x;
  float s = scale[0];
#pragma unroll
  for (int r = 0; r < 4; ++r) {
    int idx = base + r * 256;
    if (idx < nv4) {
      float4 v = ((const float4*)x)[idx];
      q[idx] = pack4_fp8(clipdiv(v.x, s), clipdiv(v.y, s),
                         clipdiv(v.z, s), clipdiv(v.w, s));
    }
  }
}

// ---------- quantize + transpose B (K x N f32 -> N x K fp8) ----------

__global__ __launch_bounds__(256) void quant_b_t(const float* __restrict__ B,
                                                 uint8_t* __restrict__ qT,
                                                 const float* __restrict__ scale) {
  __shared__ __align__(16) uint8_t lt[64 * 80];  // 64 n-rows x 64 k-bytes, +16B pad
  int tid = threadIdx.x;
  int kt = blockIdx.x * 64;  // k tile origin
  int nt = blockIdx.y * 64;  // n tile origin
  float s = scale[0];

  int kl = tid >> 4;          // 0..15
  int n4 = (tid & 15) * 4;    // 0..60
#pragma unroll
  for (int rep = 0; rep < 4; ++rep) {
    int k = kl + rep * 16;
    float4 v = *(const float4*)&B[(long)(kt + k) * N_DIM + nt + n4];
    u32 w = pack4_fp8(clipdiv(v.x, s), clipdiv(v.y, s),
                      clipdiv(v.z, s), clipdiv(v.w, s));
    lt[(n4 + 0) * 80 + k] = (uint8_t)(w & 0xff);
    lt[(n4 + 1) * 80 + k] = (uint8_t)((w >> 8) & 0xff);
    lt[(n4 + 2) * 80 + k] = (uint8_t)((w >> 16) & 0xff);
    lt[(n4 + 3) * 80 + k] = (uint8_t)(w >> 24);
  }
  __syncthreads();
  int n = tid >> 2, ch = tid & 3;
  uint4 o = *(const uint4*)&lt[n * 80 + ch * 16];
  *(uint4*)&qT[(long)(nt + n) * K_DIM + kt + ch * 16] = o;
}

// ---------- MX-fp8 GEMM: C[M,N] = (Aq @ BqT^T) * sA*sB ----------
// mfma_scale_f32_16x16x128_f8f6f4 with unit scales (e8m0=127 -> x1.0) ==
// exact fp8 e4m3 matmul at 2x the non-scaled rate.
// 128x128 tile, BK=128 (bytes), 4 waves (2x2), each wave 64x64 = 4x4 frags.
// LDS row = 128 B = 8 granules of 16 B; swizzle: phys_gcol = gcol ^ (row&7),
// applied on BOTH the global staging source and the ds_read address.

__global__ __launch_bounds__(256) void gemm_mx(const uint8_t* __restrict__ Aq,
                                               const uint8_t* __restrict__ BqT,
                                               float* __restrict__ C,
                                               const float* __restrict__ sA,
                                               const float* __restrict__ sB) {
  __shared__ __align__(16) uint8_t As[128 * 128];
  __shared__ __align__(16) uint8_t Bs[128 * 128];

  const int tid = threadIdx.x;
  const int lane = tid & 63;
  const int w = tid >> 6;
  const int wr = w >> 1, wc = w & 1;
  const long bm = (long)blockIdx.y * 128;
  const long bn = (long)blockIdx.x * 128;

  // --- staging: 1024 granules per matrix, 4 per thread ---
  const uint8_t* gA[4];
  const uint8_t* gB[4];
  uint8_t* lA[4];
  uint8_t* lB[4];
#pragma unroll
  for (int r = 0; r < 4; ++r) {
    int gid = tid + 256 * r;
    int row = gid >> 3, gc = gid & 7;
    int sc = (gc ^ (row & 7)) << 4;  // pre-swizzled source granule
    gA[r] = Aq + (bm + row) * (long)K_DIM + sc;
    gB[r] = BqT + (bn + row) * (long)K_DIM + sc;
    lA[r] = As + gid * 16;  // linear LDS dest
    lB[r] = Bs + gid * 16;
  }

  // --- fragment read offsets (loop-invariant, swizzled) ---
  // A-frag for 16x16x128: lane holds row = lane&15, k = (lane>>4)*32 + 0..31
  const int r16 = lane & 15;
  const int hi = lane >> 4;  // 0..3
  int offA[4][2], offB[4][2];
#pragma unroll
  for (int i = 0; i < 4; ++i) {
    int ra = wr * 64 + i * 16 + r16;
    int rb = wc * 64 + i * 16 + r16;
#pragma unroll
    for (int g = 0; g < 2; ++g) {
      int lg = 2 * hi + g;  // logical granule of this 16B half-fragment
      offA[i][g] = ra * 128 + ((lg ^ (ra & 7)) << 4);
      offB[i][g] = rb * 128 + ((lg ^ (rb & 7)) << 4);
    }
  }

  f32x4 acc[4][4] = {};

  for (int t = 0; t < K_DIM / 128; ++t) {
    long ko = (long)t * 128;
#pragma unroll
    for (int r = 0; r < 4; ++r) {
      gload_lds16(gA[r] + ko, lA[r]);
      gload_lds16(gB[r] + ko, lB[r]);
    }
    __syncthreads();  // drains vmcnt + lgkmcnt, then s_barrier

    v8i a[4], b[4];
#pragma unroll
    for (int i = 0; i < 4; ++i) {
      v4i alo = *(const v4i*)(As + offA[i][0]);
      v4i ahi = *(const v4i*)(As + offA[i][1]);
      a[i] = __builtin_shufflevector(alo, ahi, 0, 1, 2, 3, 4, 5, 6, 7);
      v4i blo = *(const v4i*)(Bs + offB[i][0]);
      v4i bhi = *(const v4i*)(Bs + offB[i][1]);
      b[i] = __builtin_shufflevector(blo, bhi, 0, 1, 2, 3, 4, 5, 6, 7);
    }
#pragma unroll
    for (int i = 0; i < 4; ++i)
#pragma unroll
      for (int j = 0; j < 4; ++j)
        acc[i][j] = __builtin_amdgcn_mfma_scale_f32_16x16x128_f8f6f4(
            a[i], b[j], acc[i][j], /*cbsz=fp8*/ 0, /*blgp=fp8*/ 0,
            /*opsel_a*/ 0, 0x7f7f7f7f, /*opsel_b*/ 0, 0x7f7f7f7f);
    __syncthreads();
  }

  float s = sA[0] * sB[0];
#pragma unroll
  for (int i = 0; i < 4; ++i)
#pragma unroll
    for (int j = 0; j < 4; ++j) {
      long row = bm + wr * 64 + i * 16 + hi * 4;  // C/D: row=(lane>>4)*4+q
      long col = bn + wc * 64 + j * 16 + r16;     //      col=lane&15
      float* cp = C + row * N_DIM + col;
#pragma unroll
      for (int q = 0; q < 4; ++q) cp[(long)q * N_DIM] = acc[i][j][q] * s;
    }
}

// ---------- launcher ----------

extern "C" void kernel_launch(void* const* d_in, const int* in_sizes, int n_in,
                              void* d_out, int out_size, void* d_ws, size_t ws_size,
                              hipStream_t stream) {
  const float* A = (const float*)d_in[0];   // (8192, 4096)
  const float* B = (const float*)d_in[1];   // (4096, 4096)
  const float* sA = (const float*)d_in[2];  // input_scale
  const float* sB = (const float*)d_in[4];  // kernel_scale
  float* out = (float*)d_out;

  uint8_t* Aq = (uint8_t*)d_ws;               // M*K fp8
  uint8_t* BqT = Aq + (size_t)M_DIM * K_DIM;  // N*K fp8 (transposed)

  int nv4_a = M_DIM * K_DIM / 4;
  quant_a<<<nv4_a / 1024, 256, 0, stream>>>(A, (u32*)Aq, sA, nv4_a);
  quant_b_t<<<dim3(K_DIM / 64, N_DIM / 64), 256, 0, stream>>>(B, BqT, sB);
  gemm_mx<<<dim3(N_DIM / 128, M_DIM / 128), 256, 0, stream>>>(Aq, BqT, out, sA, sB);
}